// Round 7
// baseline (350.020 us; speedup 1.0000x reference)
//
#include <hip/hip_runtime.h>
#include <math.h>

#define BB 2
#define LL 2048
#define DIMM 1024
#define HH 16
#define DD 64
#define QKV_N 3072

typedef unsigned short u16;
typedef unsigned int u32;
typedef __attribute__((ext_vector_type(8))) short short8;   // 8 x bf16
typedef __attribute__((ext_vector_type(4))) float f32x4;

__device__ __forceinline__ float bf2f(u16 h) {
    unsigned u = ((unsigned)h) << 16;
    return __uint_as_float(u);
}
__device__ __forceinline__ u16 f2bf(float f) {
    unsigned u = __float_as_uint(f);
    u += 0x7fffu + ((u >> 16) & 1u);   // round-to-nearest-even
    return (u16)(u >> 16);
}
// pack two f32 -> (bf16(hi)<<16)|bf16(lo), round-half-up
__device__ __forceinline__ u32 pack_bf2(float lo, float hi) {
    u32 a = __float_as_uint(hi) + 0x8000u;
    u32 b = __float_as_uint(lo) + 0x8000u;
    return __builtin_amdgcn_perm(a, b, 0x07060302u);
}

// ---------------- f32 -> bf16 convert (x) -------------------------------------
__global__ __launch_bounds__(256) void convx(
    const float* __restrict__ X, u16* __restrict__ Xb)
{
    int i = (blockIdx.x * 256 + threadIdx.x) * 8;
    float4 a = *(const float4*)&X[i];
    float4 b = *(const float4*)&X[i + 4];
    u16 t[8] = {f2bf(a.x), f2bf(a.y), f2bf(a.z), f2bf(a.w),
                f2bf(b.x), f2bf(b.y), f2bf(b.z), f2bf(b.w)};
    *(uint4*)&Xb[i] = *(uint4*)t;
}

// ---------------- f32 [K,N] -> bf16 [N,K] transpose-convert -------------------
__global__ __launch_bounds__(256) void convt(
    const float* __restrict__ W, u16* __restrict__ Wt, int K, int N)
{
    __shared__ u16 s[64][72];
    const int tid = threadIdx.x;
    const int k0 = blockIdx.x * 64, n0 = blockIdx.y * 64;
#pragma unroll
    for (int t = 0; t < 16; ++t) {
        int flat = t * 256 + tid;
        int kk = flat >> 6, nn = flat & 63;
        s[nn][kk] = f2bf(W[(size_t)(k0 + kk) * N + n0 + nn]);
    }
    __syncthreads();
#pragma unroll
    for (int t = 0; t < 2; ++t) {
        int chunk = t * 256 + tid;
        int nn = chunk >> 3, kc = chunk & 7;
        *(uint4*)&Wt[(size_t)(n0 + nn) * K + k0 + kc * 8] = *(uint4*)&s[nn][kc * 8];
    }
}

// ---------------- bf16 v-slice -> vt[b,h,d,l] transpose -----------------------
__global__ __launch_bounds__(256) void vtrans(
    const u16* __restrict__ qkv, u16* __restrict__ vt)
{
    __shared__ u16 s[64][72];
    const int tid = threadIdx.x;
    const int bh = blockIdx.y;           // b*16 + h
    const int b = bh >> 4, h = bh & 15;
    const int l0 = blockIdx.x * 64;
    const u16* vbase = qkv + (size_t)b * LL * QKV_N + 2048 + h * 64;
#pragma unroll
    for (int t = 0; t < 2; ++t) {
        int flat = t * 2048 + tid * 8;
        int l = flat >> 6, d = flat & 63;
        *(uint4*)&s[l][d] = *(const uint4*)&vbase[(size_t)(l0 + l) * QKV_N + d];
    }
    __syncthreads();
#pragma unroll
    for (int t = 0; t < 2; ++t) {
        int flat = t * 2048 + tid * 8;
        int d = flat >> 6, l = flat & 63;
        u16 tmp[8];
#pragma unroll
        for (int j = 0; j < 8; ++j) tmp[j] = s[l + j][d];
        *(uint4*)&vt[((size_t)bh * 64 + d) * LL + l0 + l] = *(uint4*)tmp;
    }
}

// ---------------- QKV GEMM + fused RMSNorm/RoPE epilogue ----------------------
__global__ __launch_bounds__(256) void gemm_qkv(
    const u16* __restrict__ A, const u16* __restrict__ Bt,
    u16* __restrict__ C, const float* __restrict__ pe,
    const float* __restrict__ qs, const float* __restrict__ ks)
{
    __shared__ u16 sA[128 * 72];
    __shared__ u16 sB[128 * 72];

    const int tid = threadIdx.x;
    const int wave = tid >> 6, lane = tid & 63;
    const int mIdx = lane & 15, quad = lane >> 4;
    const int wr = wave >> 1, wc = wave & 1;
    const int m0 = blockIdx.y * 128, n0 = blockIdx.x * 128;
    const int N = QKV_N, K = DIMM;

    f32x4 acc[4][4];
#pragma unroll
    for (int a = 0; a < 4; ++a)
#pragma unroll
        for (int b = 0; b < 4; ++b) acc[a][b] = (f32x4){0.f, 0.f, 0.f, 0.f};

    for (int k0 = 0; k0 < K; k0 += 64) {
#pragma unroll
        for (int t = 0; t < 4; ++t) {
            int ci = t * 256 + tid;
            int row = ci >> 3, kc = ci & 7;
            *(uint4*)&sA[row * 72 + kc * 8] =
                *(const uint4*)&A[(size_t)(m0 + row) * K + k0 + kc * 8];
            *(uint4*)&sB[row * 72 + kc * 8] =
                *(const uint4*)&Bt[(size_t)(n0 + row) * K + k0 + kc * 8];
        }
        __syncthreads();
#pragma unroll
        for (int ks2 = 0; ks2 < 2; ++ks2) {
            short8 af[4], bfr[4];
#pragma unroll
            for (int mt = 0; mt < 4; ++mt)
                af[mt] = *(const short8*)&sA[(64 * wr + 16 * mt + mIdx) * 72 + ks2 * 32 + quad * 8];
#pragma unroll
            for (int nt = 0; nt < 4; ++nt)
                bfr[nt] = *(const short8*)&sB[(64 * wc + 16 * nt + mIdx) * 72 + ks2 * 32 + quad * 8];
#pragma unroll
            for (int mt = 0; mt < 4; ++mt)
#pragma unroll
                for (int nt = 0; nt < 4; ++nt)
                    acc[mt][nt] = __builtin_amdgcn_mfma_f32_16x16x32_bf16(
                        af[mt], bfr[nt], acc[mt][nt], 0, 0, 0);
        }
        __syncthreads();
    }

    if (n0 >= 2048) {
        // v region: plain bf16 store
#pragma unroll
        for (int mt = 0; mt < 4; ++mt)
#pragma unroll
            for (int r = 0; r < 4; ++r) {
                int row = m0 + 64 * wr + 16 * mt + quad * 4 + r;
#pragma unroll
                for (int nt = 0; nt < 4; ++nt) {
                    int col = n0 + 64 * wc + 16 * nt + mIdx;
                    C[(size_t)row * N + col] = f2bf(acc[mt][nt][r]);
                }
            }
    } else {
        // q/k region: RMSNorm over head dim + RoPE; q prescaled by log2e/8.
        const float* scv = (n0 < 1024) ? qs : ks;
        const float pre = (n0 < 1024) ? 0.18033688011112042f : 1.0f;
        float scl[4];
#pragma unroll
        for (int nt = 0; nt < 4; ++nt) scl[nt] = scv[16 * nt + mIdx];

#pragma unroll
        for (int mt = 0; mt < 4; ++mt) {
#pragma unroll
            for (int r = 0; r < 4; ++r) {
                float s = 0.f;
#pragma unroll
                for (int nt = 0; nt < 4; ++nt) {
                    float a = acc[mt][nt][r];
                    s += a * a;
                }
                s += __shfl_xor(s, 1);
                s += __shfl_xor(s, 2);
                s += __shfl_xor(s, 4);
                s += __shfl_xor(s, 8);
                float rn = rsqrtf(s * (1.f / 64.f) + 1e-6f);
                int R = m0 + 64 * wr + 16 * mt + quad * 4 + r;   // = b*L + l
                size_t peo = (size_t)R * 128;
#pragma unroll
                for (int nt = 0; nt < 4; ++nt) {
                    float v = acc[mt][nt][r] * rn * scl[nt];
                    float pp = __shfl_xor(v, 1);
                    float2 pw = *(const float2*)&pe[peo + 2 * (16 * nt + mIdx)];
                    float e  = (mIdx & 1) ? pp : v;
                    float od = (mIdx & 1) ? v : pp;
                    C[(size_t)R * N + n0 + 64 * wc + 16 * nt + mIdx] =
                        f2bf((pw.x * e + pw.y * od) * pre);
                }
            }
        }
    }
}

// ---------------- proj GEMM (bf16 MFMA, f32 out + bias) -----------------------
__global__ __launch_bounds__(256) void gemm_proj(
    const u16* __restrict__ A, const u16* __restrict__ Bt,
    const float* __restrict__ bias, float* __restrict__ C)
{
    __shared__ u16 sA[128 * 72];
    __shared__ u16 sB[128 * 72];

    const int tid = threadIdx.x;
    const int wave = tid >> 6, lane = tid & 63;
    const int mIdx = lane & 15, quad = lane >> 4;
    const int wr = wave >> 1, wc = wave & 1;
    const int m0 = blockIdx.y * 128, n0 = blockIdx.x * 128;
    const int N = DIMM, K = DIMM;

    f32x4 acc[4][4];
#pragma unroll
    for (int a = 0; a < 4; ++a)
#pragma unroll
        for (int b = 0; b < 4; ++b) acc[a][b] = (f32x4){0.f, 0.f, 0.f, 0.f};

    for (int k0 = 0; k0 < K; k0 += 64) {
#pragma unroll
        for (int t = 0; t < 4; ++t) {
            int ci = t * 256 + tid;
            int row = ci >> 3, kc = ci & 7;
            *(uint4*)&sA[row * 72 + kc * 8] =
                *(const uint4*)&A[(size_t)(m0 + row) * K + k0 + kc * 8];
            *(uint4*)&sB[row * 72 + kc * 8] =
                *(const uint4*)&Bt[(size_t)(n0 + row) * K + k0 + kc * 8];
        }
        __syncthreads();
#pragma unroll
        for (int ks2 = 0; ks2 < 2; ++ks2) {
            short8 af[4], bfr[4];
#pragma unroll
            for (int mt = 0; mt < 4; ++mt)
                af[mt] = *(const short8*)&sA[(64 * wr + 16 * mt + mIdx) * 72 + ks2 * 32 + quad * 8];
#pragma unroll
            for (int nt = 0; nt < 4; ++nt)
                bfr[nt] = *(const short8*)&sB[(64 * wc + 16 * nt + mIdx) * 72 + ks2 * 32 + quad * 8];
#pragma unroll
            for (int mt = 0; mt < 4; ++mt)
#pragma unroll
                for (int nt = 0; nt < 4; ++nt)
                    acc[mt][nt] = __builtin_amdgcn_mfma_f32_16x16x32_bf16(
                        af[mt], bfr[nt], acc[mt][nt], 0, 0, 0);
        }
        __syncthreads();
    }

#pragma unroll
    for (int mt = 0; mt < 4; ++mt)
#pragma unroll
        for (int r = 0; r < 4; ++r) {
            int row = m0 + 64 * wr + 16 * mt + quad * 4 + r;
#pragma unroll
            for (int nt = 0; nt < 4; ++nt) {
                int col = n0 + 64 * wc + 16 * nt + mIdx;
                C[(size_t)row * N + col] = acc[mt][nt][r] + bias[col];
            }
        }
}

// ---------------- flash attention, 16x16x32 MFMA, 2 q-strips/wave -------------
// 256 thr = 4 waves x 32 q-rows (2 strips of 16); 128 q-rows/block; grid=512
// (2 blocks/XCD-CU... 3 blocks/CU by LDS: 52.7 KB). K-tiles of 64, double
// buffer, ONE barrier/iter, 2-deep register prefetch. K-frag and V-frag LDS
// reads are shared by both strips (per-q DS cost 1.37x lower than R5).
// S^T = mfma(K, Q): lane owns q-col mIdx -> per-lane softmax sum, no shuffles.
#define KPR 70
#define PPR 66

__global__ __launch_bounds__(256, 3) void attn_mfma(
    const u16* __restrict__ qkv, const u16* __restrict__ vt, u16* __restrict__ o)
{
    __shared__ u16 sK[2][64 * KPR];
    __shared__ u16 sVt[2][64 * KPR];
    __shared__ u16 sP[128 * PPR];

    const int tid = threadIdx.x;
    const int wave = tid >> 6;      // 0..3
    const int lane = tid & 63;
    const int mIdx = lane & 15;
    const int quad = lane >> 4;

    const int bh = blockIdx.x >> 4;    // 16 q-tiles of 128 rows per (b,h)
    const int qt = blockIdx.x & 15;
    const int b = bh >> 4, h = bh & 15;
    const int q0 = qt * 128;

    const u16* kbase = qkv + (size_t)b * LL * QKV_N + 1024 + h * 64;
    const u16* vbase = vt + (size_t)bh * 64 * LL;

    // Q B-operand fragments for the wave's 2 strips (wave-private rows)
    short8 aq[2][2];
#pragma unroll
    for (int s2 = 0; s2 < 2; ++s2) {
        const u16* qrow = qkv
            + ((size_t)(b * LL + q0 + 32 * wave + 16 * s2 + mIdx)) * QKV_N + h * 64;
        aq[s2][0] = *(const short8*)&qrow[quad * 8];
        aq[s2][1] = *(const short8*)&qrow[32 + quad * 8];
    }

    // stage tile 0 directly; prefetch tile 1 into registers
#pragma unroll
    for (int t = 0; t < 2; ++t) {
        int ci = t * 256 + tid, row = ci >> 3, c8 = (ci & 7) * 8;
        *(uint4*)&sK[0][row * KPR + c8] = *(const uint4*)&kbase[(size_t)row * QKV_N + c8];
        *(uint4*)&sVt[0][row * KPR + c8] = *(const uint4*)&vbase[(size_t)row * LL + c8];
    }
    uint4 kpre[2], vpre[2];
#pragma unroll
    for (int t = 0; t < 2; ++t) {
        int ci = t * 256 + tid, row = ci >> 3, c8 = (ci & 7) * 8;
        kpre[t] = *(const uint4*)&kbase[(size_t)(64 + row) * QKV_N + c8];
        vpre[t] = *(const uint4*)&vbase[(size_t)row * LL + 64 + c8];
    }

    float lsum[2] = {0.f, 0.f};
    f32x4 Oacc[2][4];
#pragma unroll
    for (int s2 = 0; s2 < 2; ++s2)
#pragma unroll
        for (int nb = 0; nb < 4; ++nb) Oacc[s2][nb] = (f32x4){0.f, 0.f, 0.f, 0.f};

    u16* sProw[2] = { &sP[(32 * wave + mIdx) * PPR],
                      &sP[(32 * wave + 16 + mIdx) * PPR] };

    for (int kt = 0; kt < 32; ++kt) {
        const int p = kt & 1;
        __syncthreads();   // buf p staged & visible; buf p^1 reads (kt-1) done

        // write register-prefetched tile kt+1 into buffer p^1
        if (kt + 1 < 32) {
#pragma unroll
            for (int t = 0; t < 2; ++t) {
                int ci = t * 256 + tid, row = ci >> 3, c8 = (ci & 7) * 8;
                *(uint4*)&sK[p ^ 1][row * KPR + c8] = kpre[t];
                *(uint4*)&sVt[p ^ 1][row * KPR + c8] = vpre[t];
            }
        }
        // issue global loads for tile kt+2 (a full iteration of latency slack)
        if (kt + 2 < 32) {
            const int k0n = (kt + 2) * 64;
#pragma unroll
            for (int t = 0; t < 2; ++t) {
                int ci = t * 256 + tid, row = ci >> 3, c8 = (ci & 7) * 8;
                kpre[t] = *(const uint4*)&kbase[(size_t)(k0n + row) * QKV_N + c8];
                vpre[t] = *(const uint4*)&vbase[(size_t)row * LL + k0n + c8];
            }
        }

        // ---- S^T: 64 keys x 32 q (K-frags shared across strips) ----
        f32x4 st[2][4];
#pragma unroll
        for (int nb = 0; nb < 4; ++nb) {
            short8 bk0 = *(const short8*)&sK[p][(16 * nb + mIdx) * KPR + quad * 8];
            short8 bk1 = *(const short8*)&sK[p][(16 * nb + mIdx) * KPR + 32 + quad * 8];
#pragma unroll
            for (int s2 = 0; s2 < 2; ++s2) {
                f32x4 a = (f32x4){0.f, 0.f, 0.f, 0.f};
                a = __builtin_amdgcn_mfma_f32_16x16x32_bf16(bk0, aq[s2][0], a, 0, 0, 0);
                a = __builtin_amdgcn_mfma_f32_16x16x32_bf16(bk1, aq[s2][1], a, 0, 0, 0);
                st[s2][nb] = a;
            }
        }

        // ---- softmax (exp2 domain, no running max), pack P to LDS ----
#pragma unroll
        for (int s2 = 0; s2 < 2; ++s2) {
#pragma unroll
            for (int nb = 0; nb < 4; ++nb) {
                float p0 = exp2f(st[s2][nb][0]), p1 = exp2f(st[s2][nb][1]);
                float p2 = exp2f(st[s2][nb][2]), p3 = exp2f(st[s2][nb][3]);
                lsum[s2] += (p0 + p1) + (p2 + p3);
                uint2 pr;
                pr.x = pack_bf2(p0, p1);
                pr.y = pack_bf2(p2, p3);
                *(uint2*)&sProw[s2][16 * nb + quad * 4] = pr;
            }
        }

        // ---- O += P @ V (sP rows wave-private; V-frags shared by strips) ----
        short8 pa[2][2];
#pragma unroll
        for (int s2 = 0; s2 < 2; ++s2) {
            pa[s2][0] = *(const short8*)&sProw[s2][quad * 8];
            pa[s2][1] = *(const short8*)&sProw[s2][32 + quad * 8];
        }
#pragma unroll
        for (int nb = 0; nb < 4; ++nb) {
            short8 bv0 = *(const short8*)&sVt[p][(16 * nb + mIdx) * KPR + quad * 8];
            short8 bv1 = *(const short8*)&sVt[p][(16 * nb + mIdx) * KPR + 32 + quad * 8];
#pragma unroll
            for (int s2 = 0; s2 < 2; ++s2) {
                Oacc[s2][nb] = __builtin_amdgcn_mfma_f32_16x16x32_bf16(pa[s2][0], bv0, Oacc[s2][nb], 0, 0, 0);
                Oacc[s2][nb] = __builtin_amdgcn_mfma_f32_16x16x32_bf16(pa[s2][1], bv1, Oacc[s2][nb], 0, 0, 0);
            }
        }
    }

    // epilogue: per strip, reduce l across quads, normalize, store bf16
#pragma unroll
    for (int s2 = 0; s2 < 2; ++s2) {
        float ls = lsum[s2];
        ls += __shfl_xor(ls, 16);
        ls += __shfl_xor(ls, 32);
#pragma unroll
        for (int r = 0; r < 4; ++r) {
            float lr = __shfl(ls, quad * 4 + r);
            float linv = 1.f / lr;
            int rowg = b * LL + q0 + 32 * wave + 16 * s2 + quad * 4 + r;
#pragma unroll
            for (int nb = 0; nb < 4; ++nb) {
                o[(size_t)rowg * DIMM + h * 64 + 16 * nb + mIdx] =
                    f2bf(Oacc[s2][nb][r] * linv);
            }
        }
    }
}

extern "C" void kernel_launch(void* const* d_in, const int* in_sizes, int n_in,
                              void* d_out, int out_size, void* d_ws, size_t ws_size,
                              hipStream_t stream) {
    const float* x       = (const float*)d_in[0];
    const float* pe      = (const float*)d_in[1];
    const float* w_qkv   = (const float*)d_in[2];
    const float* q_scale = (const float*)d_in[3];
    const float* k_scale = (const float*)d_in[4];
    const float* w_proj  = (const float*)d_in[5];
    const float* b_proj  = (const float*)d_in[6];
    float* out = (float*)d_out;

    char* ws = (char*)d_ws;
    u16* qkv    = (u16*)ws;  ws += (size_t)4096 * 3072 * 2;
    u16* o      = (u16*)ws;  ws += (size_t)4096 * 1024 * 2;
    u16* xb     = (u16*)ws;  ws += (size_t)4096 * 1024 * 2;
    u16* wqkvt  = (u16*)ws;  ws += (size_t)3072 * 1024 * 2;
    u16* wprojt = (u16*)ws;  ws += (size_t)1024 * 1024 * 2;
    u16* vtbuf  = (u16*)ws;  ws += (size_t)BB * HH * DD * LL * 2;

    // 0. conversions
    convx<<<(4096 * 1024) / (256 * 8), 256, 0, stream>>>(x, xb);
    convt<<<dim3(1024 / 64, QKV_N / 64), 256, 0, stream>>>(w_qkv, wqkvt, DIMM, QKV_N);
    convt<<<dim3(1024 / 64, 1024 / 64), 256, 0, stream>>>(w_proj, wprojt, DIMM, DIMM);

    // 1. fused QKV projection + RMSNorm + RoPE epilogue
    gemm_qkv<<<dim3(QKV_N / 128, (BB * LL) / 128), 256, 0, stream>>>(
        xb, wqkvt, qkv, pe, q_scale, k_scale);

    // 2. V transpose -> vt[b,h,d,l]
    vtrans<<<dim3(LL / 64, BB * HH), 256, 0, stream>>>(qkv, vtbuf);

    // 3. attention (16x16x32 MFMA, 2 q-strips/wave)
    attn_mfma<<<BB * HH * (LL / 128), 256, 0, stream>>>(qkv, vtbuf, o);

    // 4. output projection + bias (f32 out)
    gemm_proj<<<dim3(DIMM / 128, (BB * LL) / 128), 256, 0, stream>>>(
        o, wprojt, b_proj, out);
}

// Round 8
// 237.328 us; speedup vs baseline: 1.4748x; 1.4748x over previous
//
#include <hip/hip_runtime.h>
#include <math.h>

#define BB 2
#define LL 2048
#define DIMM 1024
#define HH 16
#define DD 64
#define QKV_N 3072

typedef unsigned short u16;
typedef unsigned int u32;
typedef __attribute__((ext_vector_type(8))) short short8;   // 8 x bf16
typedef __attribute__((ext_vector_type(4))) float f32x4;

__device__ __forceinline__ float bf2f(u16 h) {
    unsigned u = ((unsigned)h) << 16;
    return __uint_as_float(u);
}
__device__ __forceinline__ u16 f2bf(float f) {
    unsigned u = __float_as_uint(f);
    u += 0x7fffu + ((u >> 16) & 1u);   // round-to-nearest-even
    return (u16)(u >> 16);
}
// pack two f32 -> (bf16(hi)<<16)|bf16(lo), round-half-up
__device__ __forceinline__ u32 pack_bf2(float lo, float hi) {
    u32 a = __float_as_uint(hi) + 0x8000u;
    u32 b = __float_as_uint(lo) + 0x8000u;
    return __builtin_amdgcn_perm(a, b, 0x07060302u);
}

// ---------------- f32 -> bf16 convert (x) -------------------------------------
__global__ __launch_bounds__(256) void convx(
    const float* __restrict__ X, u16* __restrict__ Xb)
{
    int i = (blockIdx.x * 256 + threadIdx.x) * 8;
    float4 a = *(const float4*)&X[i];
    float4 b = *(const float4*)&X[i + 4];
    u16 t[8] = {f2bf(a.x), f2bf(a.y), f2bf(a.z), f2bf(a.w),
                f2bf(b.x), f2bf(b.y), f2bf(b.z), f2bf(b.w)};
    *(uint4*)&Xb[i] = *(uint4*)t;
}

// ---------------- f32 [K,N] -> bf16 [N,K] transpose-convert -------------------
__global__ __launch_bounds__(256) void convt(
    const float* __restrict__ W, u16* __restrict__ Wt, int K, int N)
{
    __shared__ u16 s[64][72];
    const int tid = threadIdx.x;
    const int k0 = blockIdx.x * 64, n0 = blockIdx.y * 64;
#pragma unroll
    for (int t = 0; t < 16; ++t) {
        int flat = t * 256 + tid;
        int kk = flat >> 6, nn = flat & 63;
        s[nn][kk] = f2bf(W[(size_t)(k0 + kk) * N + n0 + nn]);
    }
    __syncthreads();
#pragma unroll
    for (int t = 0; t < 2; ++t) {
        int chunk = t * 256 + tid;
        int nn = chunk >> 3, kc = chunk & 7;
        *(uint4*)&Wt[(size_t)(n0 + nn) * K + k0 + kc * 8] = *(uint4*)&s[nn][kc * 8];
    }
}

// ---------------- bf16 v-slice -> vt[b,h,d,l] transpose -----------------------
__global__ __launch_bounds__(256) void vtrans(
    const u16* __restrict__ qkv, u16* __restrict__ vt)
{
    __shared__ u16 s[64][72];
    const int tid = threadIdx.x;
    const int bh = blockIdx.y;           // b*16 + h
    const int b = bh >> 4, h = bh & 15;
    const int l0 = blockIdx.x * 64;
    const u16* vbase = qkv + (size_t)b * LL * QKV_N + 2048 + h * 64;
#pragma unroll
    for (int t = 0; t < 2; ++t) {
        int flat = t * 2048 + tid * 8;
        int l = flat >> 6, d = flat & 63;
        *(uint4*)&s[l][d] = *(const uint4*)&vbase[(size_t)(l0 + l) * QKV_N + d];
    }
    __syncthreads();
#pragma unroll
    for (int t = 0; t < 2; ++t) {
        int flat = t * 2048 + tid * 8;
        int d = flat >> 6, l = flat & 63;
        u16 tmp[8];
#pragma unroll
        for (int j = 0; j < 8; ++j) tmp[j] = s[l + j][d];
        *(uint4*)&vt[((size_t)bh * 64 + d) * LL + l0 + l] = *(uint4*)tmp;
    }
}

// ---------------- QKV GEMM + fused RMSNorm/RoPE epilogue ----------------------
__global__ __launch_bounds__(256) void gemm_qkv(
    const u16* __restrict__ A, const u16* __restrict__ Bt,
    u16* __restrict__ C, const float* __restrict__ pe,
    const float* __restrict__ qs, const float* __restrict__ ks)
{
    __shared__ u16 sA[128 * 72];
    __shared__ u16 sB[128 * 72];

    const int tid = threadIdx.x;
    const int wave = tid >> 6, lane = tid & 63;
    const int mIdx = lane & 15, quad = lane >> 4;
    const int wr = wave >> 1, wc = wave & 1;
    const int m0 = blockIdx.y * 128, n0 = blockIdx.x * 128;
    const int N = QKV_N, K = DIMM;

    f32x4 acc[4][4];
#pragma unroll
    for (int a = 0; a < 4; ++a)
#pragma unroll
        for (int b = 0; b < 4; ++b) acc[a][b] = (f32x4){0.f, 0.f, 0.f, 0.f};

    for (int k0 = 0; k0 < K; k0 += 64) {
#pragma unroll
        for (int t = 0; t < 4; ++t) {
            int ci = t * 256 + tid;
            int row = ci >> 3, kc = ci & 7;
            *(uint4*)&sA[row * 72 + kc * 8] =
                *(const uint4*)&A[(size_t)(m0 + row) * K + k0 + kc * 8];
            *(uint4*)&sB[row * 72 + kc * 8] =
                *(const uint4*)&Bt[(size_t)(n0 + row) * K + k0 + kc * 8];
        }
        __syncthreads();
#pragma unroll
        for (int ks2 = 0; ks2 < 2; ++ks2) {
            short8 af[4], bfr[4];
#pragma unroll
            for (int mt = 0; mt < 4; ++mt)
                af[mt] = *(const short8*)&sA[(64 * wr + 16 * mt + mIdx) * 72 + ks2 * 32 + quad * 8];
#pragma unroll
            for (int nt = 0; nt < 4; ++nt)
                bfr[nt] = *(const short8*)&sB[(64 * wc + 16 * nt + mIdx) * 72 + ks2 * 32 + quad * 8];
#pragma unroll
            for (int mt = 0; mt < 4; ++mt)
#pragma unroll
                for (int nt = 0; nt < 4; ++nt)
                    acc[mt][nt] = __builtin_amdgcn_mfma_f32_16x16x32_bf16(
                        af[mt], bfr[nt], acc[mt][nt], 0, 0, 0);
        }
        __syncthreads();
    }

    if (n0 >= 2048) {
        // v region: plain bf16 store
#pragma unroll
        for (int mt = 0; mt < 4; ++mt)
#pragma unroll
            for (int r = 0; r < 4; ++r) {
                int row = m0 + 64 * wr + 16 * mt + quad * 4 + r;
#pragma unroll
                for (int nt = 0; nt < 4; ++nt) {
                    int col = n0 + 64 * wc + 16 * nt + mIdx;
                    C[(size_t)row * N + col] = f2bf(acc[mt][nt][r]);
                }
            }
    } else {
        // q/k region: RMSNorm over head dim + RoPE; q prescaled by log2e/8.
        const float* scv = (n0 < 1024) ? qs : ks;
        const float pre = (n0 < 1024) ? 0.18033688011112042f : 1.0f;
        float scl[4];
#pragma unroll
        for (int nt = 0; nt < 4; ++nt) scl[nt] = scv[16 * nt + mIdx];

#pragma unroll
        for (int mt = 0; mt < 4; ++mt) {
#pragma unroll
            for (int r = 0; r < 4; ++r) {
                float s = 0.f;
#pragma unroll
                for (int nt = 0; nt < 4; ++nt) {
                    float a = acc[mt][nt][r];
                    s += a * a;
                }
                s += __shfl_xor(s, 1);
                s += __shfl_xor(s, 2);
                s += __shfl_xor(s, 4);
                s += __shfl_xor(s, 8);
                float rn = rsqrtf(s * (1.f / 64.f) + 1e-6f);
                int R = m0 + 64 * wr + 16 * mt + quad * 4 + r;   // = b*L + l
                size_t peo = (size_t)R * 128;
#pragma unroll
                for (int nt = 0; nt < 4; ++nt) {
                    float v = acc[mt][nt][r] * rn * scl[nt];
                    float pp = __shfl_xor(v, 1);
                    float2 pw = *(const float2*)&pe[peo + 2 * (16 * nt + mIdx)];
                    float e  = (mIdx & 1) ? pp : v;
                    float od = (mIdx & 1) ? v : pp;
                    C[(size_t)R * N + n0 + 64 * wc + 16 * nt + mIdx] =
                        f2bf((pw.x * e + pw.y * od) * pre);
                }
            }
        }
    }
}

// ---------------- proj GEMM (bf16 MFMA, f32 out + bias) -----------------------
__global__ __launch_bounds__(256) void gemm_proj(
    const u16* __restrict__ A, const u16* __restrict__ Bt,
    const float* __restrict__ bias, float* __restrict__ C)
{
    __shared__ u16 sA[128 * 72];
    __shared__ u16 sB[128 * 72];

    const int tid = threadIdx.x;
    const int wave = tid >> 6, lane = tid & 63;
    const int mIdx = lane & 15, quad = lane >> 4;
    const int wr = wave >> 1, wc = wave & 1;
    const int m0 = blockIdx.y * 128, n0 = blockIdx.x * 128;
    const int N = DIMM, K = DIMM;

    f32x4 acc[4][4];
#pragma unroll
    for (int a = 0; a < 4; ++a)
#pragma unroll
        for (int b = 0; b < 4; ++b) acc[a][b] = (f32x4){0.f, 0.f, 0.f, 0.f};

    for (int k0 = 0; k0 < K; k0 += 64) {
#pragma unroll
        for (int t = 0; t < 4; ++t) {
            int ci = t * 256 + tid;
            int row = ci >> 3, kc = ci & 7;
            *(uint4*)&sA[row * 72 + kc * 8] =
                *(const uint4*)&A[(size_t)(m0 + row) * K + k0 + kc * 8];
            *(uint4*)&sB[row * 72 + kc * 8] =
                *(const uint4*)&Bt[(size_t)(n0 + row) * K + k0 + kc * 8];
        }
        __syncthreads();
#pragma unroll
        for (int ks2 = 0; ks2 < 2; ++ks2) {
            short8 af[4], bfr[4];
#pragma unroll
            for (int mt = 0; mt < 4; ++mt)
                af[mt] = *(const short8*)&sA[(64 * wr + 16 * mt + mIdx) * 72 + ks2 * 32 + quad * 8];
#pragma unroll
            for (int nt = 0; nt < 4; ++nt)
                bfr[nt] = *(const short8*)&sB[(64 * wc + 16 * nt + mIdx) * 72 + ks2 * 32 + quad * 8];
#pragma unroll
            for (int mt = 0; mt < 4; ++mt)
#pragma unroll
                for (int nt = 0; nt < 4; ++nt)
                    acc[mt][nt] = __builtin_amdgcn_mfma_f32_16x16x32_bf16(
                        af[mt], bfr[nt], acc[mt][nt], 0, 0, 0);
        }
        __syncthreads();
    }

#pragma unroll
    for (int mt = 0; mt < 4; ++mt)
#pragma unroll
        for (int r = 0; r < 4; ++r) {
            int row = m0 + 64 * wr + 16 * mt + quad * 4 + r;
#pragma unroll
            for (int nt = 0; nt < 4; ++nt) {
                int col = n0 + 64 * wc + 16 * nt + mIdx;
                C[(size_t)row * N + col] = acc[mt][nt][r] + bias[col];
            }
        }
}

// ---------------- flash attention, bf16 MFMA, S^T formulation (R5 proven) -----
// 512 threads = 8 waves; 128 q-rows/block (16 per wave); k-tiles of 64,
// double-buffered, 1 barrier/iter. S^T = mfma(K-frag, Q-frag): each lane owns
// one q-row (col = mIdx) -> softmax sum is per-lane, NO shuffles in loop.
// No running max: scores are statistically bounded; exp2 cannot overflow f32
// until s > 128 (unreachable), softmax is scale-invariant so result identical.
// NOTE: prefetch is an immediate global-load -> LDS-store inside the iteration
// (no registers held across __syncthreads) — R7's cross-iter register prefetch
// caused scratch spilling (WRITE_SIZE 8->184 MB). Keep this form.
#define PR 72

__global__ __launch_bounds__(512, 4) void attn_mfma(
    const u16* __restrict__ qkv, const u16* __restrict__ vt, u16* __restrict__ o)
{
    __shared__ u16 sK[2][64 * PR];
    __shared__ u16 sVt[2][64 * PR];
    __shared__ u16 sP[128 * PR];

    const int tid = threadIdx.x;
    const int wave = tid >> 6;     // 0..7
    const int lane = tid & 63;
    const int mIdx = lane & 15;
    const int quad = lane >> 4;

    const int bh = blockIdx.x >> 4;   // 16 q-tiles of 128 rows per (b,h)
    const int qt = blockIdx.x & 15;
    const int b = bh >> 4, h = bh & 15;
    const int q0 = qt * 128;

    const u16* kbase = qkv + (size_t)b * LL * QKV_N + 1024 + h * 64;
    const u16* vbase = vt + (size_t)bh * 64 * LL;

    // Q fragment straight from global (wave-private rows); used as B-operand.
    const u16* qrow = qkv + (size_t)b * LL * QKV_N + h * 64
                      + (size_t)(q0 + 16 * wave + mIdx) * QKV_N;
    short8 aq0 = *(const short8*)&qrow[quad * 8];
    short8 aq1 = *(const short8*)&qrow[32 + quad * 8];

    // staging: 512 threads cover one 64x64 tile (1 uint4 each)
    const int sr = tid >> 3;        // row 0..63
    const int sc = (tid & 7) * 8;   // col chunk

    // preload tile 0
    {
        uint4 kv4 = *(const uint4*)&kbase[(size_t)sr * QKV_N + sc];
        uint4 vv4 = *(const uint4*)&vbase[(size_t)sr * LL + sc];
        *(uint4*)&sK[0][sr * PR + sc] = kv4;
        *(uint4*)&sVt[0][sr * PR + sc] = vv4;
    }

    float lsum = 0.f;
    f32x4 Oacc[4];
#pragma unroll
    for (int nb = 0; nb < 4; ++nb) Oacc[nb] = (f32x4){0.f, 0.f, 0.f, 0.f};

    u16* sProw = &sP[(16 * wave + mIdx) * PR];

    for (int kt = 0; kt < 32; ++kt) {
        const int p = kt & 1;
        __syncthreads();   // tile p staged; buffer p^1 free (read in iter kt-1)

        // prefetch tile kt+1 into buffer p^1 (overlaps compute below)
        if (kt + 1 < 32) {
            const int k0n = (kt + 1) * 64;
            uint4 kv4 = *(const uint4*)&kbase[(size_t)(k0n + sr) * QKV_N + sc];
            uint4 vv4 = *(const uint4*)&vbase[(size_t)sr * LL + k0n + sc];
            *(uint4*)&sK[p ^ 1][sr * PR + sc] = kv4;
            *(uint4*)&sVt[p ^ 1][sr * PR + sc] = vv4;
        }

        // ---- S^T strip: D[key][q] = mfma(A=K-frag, B=Q-frag) ----
#pragma unroll
        for (int nb = 0; nb < 4; ++nb) {
            short8 bk0 = *(const short8*)&sK[p][(16 * nb + mIdx) * PR + quad * 8];
            short8 bk1 = *(const short8*)&sK[p][(16 * nb + mIdx) * PR + 32 + quad * 8];
            f32x4 st = (f32x4){0.f, 0.f, 0.f, 0.f};
            st = __builtin_amdgcn_mfma_f32_16x16x32_bf16(bk0, aq0, st, 0, 0, 0);
            st = __builtin_amdgcn_mfma_f32_16x16x32_bf16(bk1, aq1, st, 0, 0, 0);

            // p = exp2(s), per-lane row-sum (this lane's q-row = mIdx),
            // pack 4 bf16 and one ds_write_b64 (keys 16*nb+quad*4 .. +3)
            float p0 = exp2f(st[0]), p1 = exp2f(st[1]);
            float p2 = exp2f(st[2]), p3 = exp2f(st[3]);
            lsum += (p0 + p1) + (p2 + p3);
            u32 w0 = pack_bf2(p0, p1);
            u32 w1 = pack_bf2(p2, p3);
            uint2 wpair; wpair.x = w0; wpair.y = w1;
            *(uint2*)&sProw[16 * nb + quad * 4] = wpair;
        }
        // sP rows are written and read by the same wave -> no barrier.

        // ---- O += P @ V ----
        short8 pa0 = *(const short8*)&sProw[quad * 8];
        short8 pa1 = *(const short8*)&sProw[32 + quad * 8];
#pragma unroll
        for (int nb = 0; nb < 4; ++nb) {
            short8 bv0 = *(const short8*)&sVt[p][(16 * nb + mIdx) * PR + quad * 8];
            short8 bv1 = *(const short8*)&sVt[p][(16 * nb + mIdx) * PR + 32 + quad * 8];
            Oacc[nb] = __builtin_amdgcn_mfma_f32_16x16x32_bf16(pa0, bv0, Oacc[nb], 0, 0, 0);
            Oacc[nb] = __builtin_amdgcn_mfma_f32_16x16x32_bf16(pa1, bv1, Oacc[nb], 0, 0, 0);
        }
    }

    // final l: reduce per-lane partial sums across the 4 quads (2 shuffles),
    // then each lane fetches l for its epilogue rows quad*4+r via shfl.
    lsum += __shfl_xor(lsum, 16);
    lsum += __shfl_xor(lsum, 32);

#pragma unroll
    for (int r = 0; r < 4; ++r) {
        float lr = __shfl(lsum, quad * 4 + r);   // lane (quad*4+r) has mIdx==quad*4+r
        float linv = 1.f / lr;
        int rowg = b * LL + q0 + 16 * wave + quad * 4 + r;
#pragma unroll
        for (int nb = 0; nb < 4; ++nb) {
            o[(size_t)rowg * DIMM + h * 64 + 16 * nb + mIdx] = f2bf(Oacc[nb][r] * linv);
        }
    }
}

extern "C" void kernel_launch(void* const* d_in, const int* in_sizes, int n_in,
                              void* d_out, int out_size, void* d_ws, size_t ws_size,
                              hipStream_t stream) {
    const float* x       = (const float*)d_in[0];
    const float* pe      = (const float*)d_in[1];
    const float* w_qkv   = (const float*)d_in[2];
    const float* q_scale = (const float*)d_in[3];
    const float* k_scale = (const float*)d_in[4];
    const float* w_proj  = (const float*)d_in[5];
    const float* b_proj  = (const float*)d_in[6];
    float* out = (float*)d_out;

    char* ws = (char*)d_ws;
    u16* qkv    = (u16*)ws;  ws += (size_t)4096 * 3072 * 2;
    u16* o      = (u16*)ws;  ws += (size_t)4096 * 1024 * 2;
    u16* xb     = (u16*)ws;  ws += (size_t)4096 * 1024 * 2;
    u16* wqkvt  = (u16*)ws;  ws += (size_t)3072 * 1024 * 2;
    u16* wprojt = (u16*)ws;  ws += (size_t)1024 * 1024 * 2;
    u16* vtbuf  = (u16*)ws;  ws += (size_t)BB * HH * DD * LL * 2;

    // 0. conversions
    convx<<<(4096 * 1024) / (256 * 8), 256, 0, stream>>>(x, xb);
    convt<<<dim3(1024 / 64, QKV_N / 64), 256, 0, stream>>>(w_qkv, wqkvt, DIMM, QKV_N);
    convt<<<dim3(1024 / 64, 1024 / 64), 256, 0, stream>>>(w_proj, wprojt, DIMM, DIMM);

    // 1. fused QKV projection + RMSNorm + RoPE epilogue
    gemm_qkv<<<dim3(QKV_N / 128, (BB * LL) / 128), 256, 0, stream>>>(
        xb, wqkvt, qkv, pe, q_scale, k_scale);

    // 2. V transpose -> vt[b,h,d,l]
    vtrans<<<dim3(LL / 64, BB * HH), 256, 0, stream>>>(qkv, vtbuf);

    // 3. attention (R5-proven 16x16x32 MFMA, S^T formulation)
    attn_mfma<<<BB * HH * (LL / 128), 512, 0, stream>>>(qkv, vtbuf, o);

    // 4. output projection + bias (f32 out)
    gemm_proj<<<dim3(DIMM / 128, (BB * LL) / 128), 256, 0, stream>>>(
        o, wprojt, b_proj, out);
}

// Round 9
// 227.205 us; speedup vs baseline: 1.5405x; 1.0446x over previous
//
#include <hip/hip_runtime.h>
#include <math.h>

#define BB 2
#define LL 2048
#define DIMM 1024
#define HH 16
#define DD 64
#define QKV_N 3072

typedef unsigned short u16;
typedef unsigned int u32;
typedef __attribute__((ext_vector_type(8))) short short8;   // 8 x bf16
typedef __attribute__((ext_vector_type(4))) float f32x4;

__device__ __forceinline__ float bf2f(u16 h) {
    unsigned u = ((unsigned)h) << 16;
    return __uint_as_float(u);
}
__device__ __forceinline__ u16 f2bf(float f) {
    unsigned u = __float_as_uint(f);
    u += 0x7fffu + ((u >> 16) & 1u);   // round-to-nearest-even
    return (u16)(u >> 16);
}
// pack two f32 -> (bf16(hi)<<16)|bf16(lo), round-half-up
__device__ __forceinline__ u32 pack_bf2(float lo, float hi) {
    u32 a = __float_as_uint(hi) + 0x8000u;
    u32 b = __float_as_uint(lo) + 0x8000u;
    return __builtin_amdgcn_perm(a, b, 0x07060302u);
}
// async global->LDS, 16B per lane; LDS dst is wave-uniform base + lane*16
__device__ __forceinline__ void gload16(const u16* g, u16* l) {
    __builtin_amdgcn_global_load_lds(
        (const __attribute__((address_space(1))) void*)g,
        (__attribute__((address_space(3))) void*)l, 16, 0, 0);
}

// ---------------- f32 -> bf16 convert (x) -------------------------------------
__global__ __launch_bounds__(256) void convx(
    const float* __restrict__ X, u16* __restrict__ Xb)
{
    int i = (blockIdx.x * 256 + threadIdx.x) * 8;
    float4 a = *(const float4*)&X[i];
    float4 b = *(const float4*)&X[i + 4];
    u16 t[8] = {f2bf(a.x), f2bf(a.y), f2bf(a.z), f2bf(a.w),
                f2bf(b.x), f2bf(b.y), f2bf(b.z), f2bf(b.w)};
    *(uint4*)&Xb[i] = *(uint4*)t;
}

// ---------------- f32 [K,N] -> bf16 [N,K] transpose-convert -------------------
__global__ __launch_bounds__(256) void convt(
    const float* __restrict__ W, u16* __restrict__ Wt, int K, int N)
{
    __shared__ u16 s[64][72];
    const int tid = threadIdx.x;
    const int k0 = blockIdx.x * 64, n0 = blockIdx.y * 64;
#pragma unroll
    for (int t = 0; t < 16; ++t) {
        int flat = t * 256 + tid;
        int kk = flat >> 6, nn = flat & 63;
        s[nn][kk] = f2bf(W[(size_t)(k0 + kk) * N + n0 + nn]);
    }
    __syncthreads();
#pragma unroll
    for (int t = 0; t < 2; ++t) {
        int chunk = t * 256 + tid;
        int nn = chunk >> 3, kc = chunk & 7;
        *(uint4*)&Wt[(size_t)(n0 + nn) * K + k0 + kc * 8] = *(uint4*)&s[nn][kc * 8];
    }
}

// ---------------- bf16 v-slice -> vt[b,h,d,l] transpose -----------------------
__global__ __launch_bounds__(256) void vtrans(
    const u16* __restrict__ qkv, u16* __restrict__ vt)
{
    __shared__ u16 s[64][72];
    const int tid = threadIdx.x;
    const int bh = blockIdx.y;           // b*16 + h
    const int b = bh >> 4, h = bh & 15;
    const int l0 = blockIdx.x * 64;
    const u16* vbase = qkv + (size_t)b * LL * QKV_N + 2048 + h * 64;
#pragma unroll
    for (int t = 0; t < 2; ++t) {
        int flat = t * 2048 + tid * 8;
        int l = flat >> 6, d = flat & 63;
        *(uint4*)&s[l][d] = *(const uint4*)&vbase[(size_t)(l0 + l) * QKV_N + d];
    }
    __syncthreads();
#pragma unroll
    for (int t = 0; t < 2; ++t) {
        int flat = t * 2048 + tid * 8;
        int d = flat >> 6, l = flat & 63;
        u16 tmp[8];
#pragma unroll
        for (int j = 0; j < 8; ++j) tmp[j] = s[l + j][d];
        *(uint4*)&vt[((size_t)bh * 64 + d) * LL + l0 + l] = *(uint4*)tmp;
    }
}

// ---------------- QKV GEMM (global_load_lds staging) + RMS/RoPE epilogue ------
// m97-style: 128x128 tile, BK=64, single-buffer LDS, 2-barrier K-loop,
// async 16B/lane staging. Unpadded LDS rows (wave-uniform-dst constraint)
// with XOR chunk swizzle (c ^= row&7) applied on the GLOBAL source address,
// so b128 frag reads spread banks (<=2-way per quad).
__global__ __launch_bounds__(256) void gemm_qkv(
    const u16* __restrict__ A, const u16* __restrict__ Bt,
    u16* __restrict__ C, const float* __restrict__ pe,
    const float* __restrict__ qs, const float* __restrict__ ks)
{
    __shared__ u16 sA[128 * 64];
    __shared__ u16 sB[128 * 64];

    const int tid = threadIdx.x;
    const int wave = tid >> 6, lane = tid & 63;
    const int mIdx = lane & 15, quad = lane >> 4;
    const int wr = wave >> 1, wc = wave & 1;
    const int m0 = blockIdx.y * 128, n0 = blockIdx.x * 128;
    const int N = QKV_N, K = DIMM;
    const int lr = lane >> 3, lc = lane & 7;   // staging row-in-group / chunk

    f32x4 acc[4][4];
#pragma unroll
    for (int a = 0; a < 4; ++a)
#pragma unroll
        for (int b = 0; b < 4; ++b) acc[a][b] = (f32x4){0.f, 0.f, 0.f, 0.f};

    for (int k0 = 0; k0 < K; k0 += 64) {
        // async staging: 4 A + 4 B instructions per wave (8 rows each)
#pragma unroll
        for (int j = 0; j < 4; ++j) {
            int r0 = 32 * wave + 8 * j + lr;
            int kc = 8 * (lc ^ (r0 & 7));
            gload16(&A[(size_t)(m0 + r0) * K + k0 + kc], &sA[(32 * wave + 8 * j) * 64]);
            gload16(&Bt[(size_t)(n0 + r0) * K + k0 + kc], &sB[(32 * wave + 8 * j) * 64]);
        }
        __syncthreads();   // drains vmcnt(0): staged data visible
#pragma unroll
        for (int ks2 = 0; ks2 < 2; ++ks2) {
            short8 af[4], bfr[4];
#pragma unroll
            for (int mt = 0; mt < 4; ++mt) {
                int Ra = 64 * wr + 16 * mt + mIdx;
                af[mt] = *(const short8*)&sA[Ra * 64 + 8 * ((ks2 * 4 + quad) ^ (Ra & 7))];
            }
#pragma unroll
            for (int nt = 0; nt < 4; ++nt) {
                int Rb = 64 * wc + 16 * nt + mIdx;
                bfr[nt] = *(const short8*)&sB[Rb * 64 + 8 * ((ks2 * 4 + quad) ^ (Rb & 7))];
            }
#pragma unroll
            for (int mt = 0; mt < 4; ++mt)
#pragma unroll
                for (int nt = 0; nt < 4; ++nt)
                    acc[mt][nt] = __builtin_amdgcn_mfma_f32_16x16x32_bf16(
                        af[mt], bfr[nt], acc[mt][nt], 0, 0, 0);
        }
        __syncthreads();   // all reads done before next tile overwrites
    }

    if (n0 >= 2048) {
        // v region: plain bf16 store
#pragma unroll
        for (int mt = 0; mt < 4; ++mt)
#pragma unroll
            for (int r = 0; r < 4; ++r) {
                int row = m0 + 64 * wr + 16 * mt + quad * 4 + r;
#pragma unroll
                for (int nt = 0; nt < 4; ++nt) {
                    int col = n0 + 64 * wc + 16 * nt + mIdx;
                    C[(size_t)row * N + col] = f2bf(acc[mt][nt][r]);
                }
            }
    } else {
        // q/k region: RMSNorm over head dim + RoPE; q prescaled by log2e/8.
        const float* scv = (n0 < 1024) ? qs : ks;
        const float pre = (n0 < 1024) ? 0.18033688011112042f : 1.0f;
        float scl[4];
#pragma unroll
        for (int nt = 0; nt < 4; ++nt) scl[nt] = scv[16 * nt + mIdx];

#pragma unroll
        for (int mt = 0; mt < 4; ++mt) {
#pragma unroll
            for (int r = 0; r < 4; ++r) {
                float s = 0.f;
#pragma unroll
                for (int nt = 0; nt < 4; ++nt) {
                    float a = acc[mt][nt][r];
                    s += a * a;
                }
                s += __shfl_xor(s, 1);
                s += __shfl_xor(s, 2);
                s += __shfl_xor(s, 4);
                s += __shfl_xor(s, 8);
                float rn = rsqrtf(s * (1.f / 64.f) + 1e-6f);
                int R = m0 + 64 * wr + 16 * mt + quad * 4 + r;   // = b*L + l
                size_t peo = (size_t)R * 128;
#pragma unroll
                for (int nt = 0; nt < 4; ++nt) {
                    float v = acc[mt][nt][r] * rn * scl[nt];
                    float pp = __shfl_xor(v, 1);
                    float2 pw = *(const float2*)&pe[peo + 2 * (16 * nt + mIdx)];
                    float e  = (mIdx & 1) ? pp : v;
                    float od = (mIdx & 1) ? v : pp;
                    C[(size_t)R * N + n0 + 64 * wc + 16 * nt + mIdx] =
                        f2bf((pw.x * e + pw.y * od) * pre);
                }
            }
        }
    }
}

// ---------------- proj GEMM (global_load_lds staging, 64x128 tile) ------------
// 64x128 tile -> 512 blocks = 2/CU (avoid 1-block/CU latency exposure).
__global__ __launch_bounds__(256) void gemm_proj(
    const u16* __restrict__ A, const u16* __restrict__ Bt,
    const float* __restrict__ bias, float* __restrict__ C)
{
    __shared__ u16 sA[64 * 64];
    __shared__ u16 sB[128 * 64];

    const int tid = threadIdx.x;
    const int wave = tid >> 6, lane = tid & 63;
    const int mIdx = lane & 15, quad = lane >> 4;
    const int wr = wave >> 1, wc = wave & 1;   // 2x2 waves of 32x64
    const int m0 = blockIdx.y * 64, n0 = blockIdx.x * 128;
    const int N = DIMM, K = DIMM;
    const int lr = lane >> 3, lc = lane & 7;

    f32x4 acc[2][4];
#pragma unroll
    for (int a = 0; a < 2; ++a)
#pragma unroll
        for (int b = 0; b < 4; ++b) acc[a][b] = (f32x4){0.f, 0.f, 0.f, 0.f};

    for (int k0 = 0; k0 < K; k0 += 64) {
#pragma unroll
        for (int j = 0; j < 2; ++j) {       // A: 64 rows, 2 instr/wave
            int r0 = 16 * wave + 8 * j + lr;
            int kc = 8 * (lc ^ (r0 & 7));
            gload16(&A[(size_t)(m0 + r0) * K + k0 + kc], &sA[(16 * wave + 8 * j) * 64]);
        }
#pragma unroll
        for (int j = 0; j < 4; ++j) {       // B: 128 rows, 4 instr/wave
            int r0 = 32 * wave + 8 * j + lr;
            int kc = 8 * (lc ^ (r0 & 7));
            gload16(&Bt[(size_t)(n0 + r0) * K + k0 + kc], &sB[(32 * wave + 8 * j) * 64]);
        }
        __syncthreads();
#pragma unroll
        for (int ks2 = 0; ks2 < 2; ++ks2) {
            short8 af[2], bfr[4];
#pragma unroll
            for (int mt = 0; mt < 2; ++mt) {
                int Ra = 32 * wr + 16 * mt + mIdx;
                af[mt] = *(const short8*)&sA[Ra * 64 + 8 * ((ks2 * 4 + quad) ^ (Ra & 7))];
            }
#pragma unroll
            for (int nt = 0; nt < 4; ++nt) {
                int Rb = 64 * wc + 16 * nt + mIdx;
                bfr[nt] = *(const short8*)&sB[Rb * 64 + 8 * ((ks2 * 4 + quad) ^ (Rb & 7))];
            }
#pragma unroll
            for (int mt = 0; mt < 2; ++mt)
#pragma unroll
                for (int nt = 0; nt < 4; ++nt)
                    acc[mt][nt] = __builtin_amdgcn_mfma_f32_16x16x32_bf16(
                        af[mt], bfr[nt], acc[mt][nt], 0, 0, 0);
        }
        __syncthreads();
    }

#pragma unroll
    for (int mt = 0; mt < 2; ++mt)
#pragma unroll
        for (int r = 0; r < 4; ++r) {
            int row = m0 + 32 * wr + 16 * mt + quad * 4 + r;
#pragma unroll
            for (int nt = 0; nt < 4; ++nt) {
                int col = n0 + 64 * wc + 16 * nt + mIdx;
                C[(size_t)row * N + col] = acc[mt][nt][r] + bias[col];
            }
        }
}

// ---------------- flash attention, bf16 MFMA, S^T formulation (R5 proven) -----
#define PR 72

__global__ __launch_bounds__(512, 4) void attn_mfma(
    const u16* __restrict__ qkv, const u16* __restrict__ vt, u16* __restrict__ o)
{
    __shared__ u16 sK[2][64 * PR];
    __shared__ u16 sVt[2][64 * PR];
    __shared__ u16 sP[128 * PR];

    const int tid = threadIdx.x;
    const int wave = tid >> 6;     // 0..7
    const int lane = tid & 63;
    const int mIdx = lane & 15;
    const int quad = lane >> 4;

    const int bh = blockIdx.x >> 4;   // 16 q-tiles of 128 rows per (b,h)
    const int qt = blockIdx.x & 15;
    const int b = bh >> 4, h = bh & 15;
    const int q0 = qt * 128;

    const u16* kbase = qkv + (size_t)b * LL * QKV_N + 1024 + h * 64;
    const u16* vbase = vt + (size_t)bh * 64 * LL;

    // Q fragment straight from global (wave-private rows); used as B-operand.
    const u16* qrow = qkv + (size_t)b * LL * QKV_N + h * 64
                      + (size_t)(q0 + 16 * wave + mIdx) * QKV_N;
    short8 aq0 = *(const short8*)&qrow[quad * 8];
    short8 aq1 = *(const short8*)&qrow[32 + quad * 8];

    // staging: 512 threads cover one 64x64 tile (1 uint4 each)
    const int sr = tid >> 3;        // row 0..63
    const int sc = (tid & 7) * 8;   // col chunk

    // preload tile 0
    {
        uint4 kv4 = *(const uint4*)&kbase[(size_t)sr * QKV_N + sc];
        uint4 vv4 = *(const uint4*)&vbase[(size_t)sr * LL + sc];
        *(uint4*)&sK[0][sr * PR + sc] = kv4;
        *(uint4*)&sVt[0][sr * PR + sc] = vv4;
    }

    float lsum = 0.f;
    f32x4 Oacc[4];
#pragma unroll
    for (int nb = 0; nb < 4; ++nb) Oacc[nb] = (f32x4){0.f, 0.f, 0.f, 0.f};

    u16* sProw = &sP[(16 * wave + mIdx) * PR];

    for (int kt = 0; kt < 32; ++kt) {
        const int p = kt & 1;
        __syncthreads();   // tile p staged; buffer p^1 free (read in iter kt-1)

        // prefetch tile kt+1 into buffer p^1 (overlaps compute below)
        if (kt + 1 < 32) {
            const int k0n = (kt + 1) * 64;
            uint4 kv4 = *(const uint4*)&kbase[(size_t)(k0n + sr) * QKV_N + sc];
            uint4 vv4 = *(const uint4*)&vbase[(size_t)sr * LL + k0n + sc];
            *(uint4*)&sK[p ^ 1][sr * PR + sc] = kv4;
            *(uint4*)&sVt[p ^ 1][sr * PR + sc] = vv4;
        }

        // ---- S^T strip: D[key][q] = mfma(A=K-frag, B=Q-frag) ----
#pragma unroll
        for (int nb = 0; nb < 4; ++nb) {
            short8 bk0 = *(const short8*)&sK[p][(16 * nb + mIdx) * PR + quad * 8];
            short8 bk1 = *(const short8*)&sK[p][(16 * nb + mIdx) * PR + 32 + quad * 8];
            f32x4 st = (f32x4){0.f, 0.f, 0.f, 0.f};
            st = __builtin_amdgcn_mfma_f32_16x16x32_bf16(bk0, aq0, st, 0, 0, 0);
            st = __builtin_amdgcn_mfma_f32_16x16x32_bf16(bk1, aq1, st, 0, 0, 0);

            float p0 = exp2f(st[0]), p1 = exp2f(st[1]);
            float p2 = exp2f(st[2]), p3 = exp2f(st[3]);
            lsum += (p0 + p1) + (p2 + p3);
            u32 w0 = pack_bf2(p0, p1);
            u32 w1 = pack_bf2(p2, p3);
            uint2 wpair; wpair.x = w0; wpair.y = w1;
            *(uint2*)&sProw[16 * nb + quad * 4] = wpair;
        }
        // sP rows are written and read by the same wave -> no barrier.

        // ---- O += P @ V ----
        short8 pa0 = *(const short8*)&sProw[quad * 8];
        short8 pa1 = *(const short8*)&sProw[32 + quad * 8];
#pragma unroll
        for (int nb = 0; nb < 4; ++nb) {
            short8 bv0 = *(const short8*)&sVt[p][(16 * nb + mIdx) * PR + quad * 8];
            short8 bv1 = *(const short8*)&sVt[p][(16 * nb + mIdx) * PR + 32 + quad * 8];
            Oacc[nb] = __builtin_amdgcn_mfma_f32_16x16x32_bf16(pa0, bv0, Oacc[nb], 0, 0, 0);
            Oacc[nb] = __builtin_amdgcn_mfma_f32_16x16x32_bf16(pa1, bv1, Oacc[nb], 0, 0, 0);
        }
    }

    // final l: reduce per-lane partial sums across the 4 quads (2 shuffles),
    // then each lane fetches l for its epilogue rows quad*4+r via shfl.
    lsum += __shfl_xor(lsum, 16);
    lsum += __shfl_xor(lsum, 32);

#pragma unroll
    for (int r = 0; r < 4; ++r) {
        float lr = __shfl(lsum, quad * 4 + r);   // lane (quad*4+r) has mIdx==quad*4+r
        float linv = 1.f / lr;
        int rowg = b * LL + q0 + 16 * wave + quad * 4 + r;
#pragma unroll
        for (int nb = 0; nb < 4; ++nb) {
            o[(size_t)rowg * DIMM + h * 64 + 16 * nb + mIdx] = f2bf(Oacc[nb][r] * linv);
        }
    }
}

extern "C" void kernel_launch(void* const* d_in, const int* in_sizes, int n_in,
                              void* d_out, int out_size, void* d_ws, size_t ws_size,
                              hipStream_t stream) {
    const float* x       = (const float*)d_in[0];
    const float* pe      = (const float*)d_in[1];
    const float* w_qkv   = (const float*)d_in[2];
    const float* q_scale = (const float*)d_in[3];
    const float* k_scale = (const float*)d_in[4];
    const float* w_proj  = (const float*)d_in[5];
    const float* b_proj  = (const float*)d_in[6];
    float* out = (float*)d_out;

    char* ws = (char*)d_ws;
    u16* qkv    = (u16*)ws;  ws += (size_t)4096 * 3072 * 2;
    u16* o      = (u16*)ws;  ws += (size_t)4096 * 1024 * 2;
    u16* xb     = (u16*)ws;  ws += (size_t)4096 * 1024 * 2;
    u16* wqkvt  = (u16*)ws;  ws += (size_t)3072 * 1024 * 2;
    u16* wprojt = (u16*)ws;  ws += (size_t)1024 * 1024 * 2;
    u16* vtbuf  = (u16*)ws;  ws += (size_t)BB * HH * DD * LL * 2;

    // 0. conversions
    convx<<<(4096 * 1024) / (256 * 8), 256, 0, stream>>>(x, xb);
    convt<<<dim3(1024 / 64, QKV_N / 64), 256, 0, stream>>>(w_qkv, wqkvt, DIMM, QKV_N);
    convt<<<dim3(1024 / 64, 1024 / 64), 256, 0, stream>>>(w_proj, wprojt, DIMM, DIMM);

    // 1. fused QKV projection + RMSNorm + RoPE epilogue (async staging)
    gemm_qkv<<<dim3(QKV_N / 128, (BB * LL) / 128), 256, 0, stream>>>(
        xb, wqkvt, qkv, pe, q_scale, k_scale);

    // 2. V transpose -> vt[b,h,d,l]
    vtrans<<<dim3(LL / 64, BB * HH), 256, 0, stream>>>(qkv, vtbuf);

    // 3. attention (R5-proven 16x16x32 MFMA, S^T formulation)
    attn_mfma<<<BB * HH * (LL / 128), 512, 0, stream>>>(qkv, vtbuf, o);

    // 4. output projection + bias (async staging, 64x128 tile, f32 out)
    gemm_proj<<<dim3(DIMM / 128, (BB * LL) / 64), 256, 0, stream>>>(
        o, wprojt, b_proj, out);
}